// Round 5
// baseline (593.809 us; speedup 1.0000x reference)
//
#include <hip/hip_runtime.h>
#include <hip/hip_bf16.h>

typedef __bf16 bf16_t;
typedef bf16_t bf16x8 __attribute__((ext_vector_type(8)));
typedef float floatx4 __attribute__((ext_vector_type(4)));

#define MFMA16(a, b, c) __builtin_amdgcn_mfma_f32_16x16x32_bf16((a), (b), (c), 0, 0, 0)

// ---------------------------------------------------------------------------
// One-time weight convert fp32 -> bf16 into workspace.
// wb layout: [0 .. 196607] = w_qkv (768x256), [196608 .. 262143] = w_proj.
// ---------------------------------------------------------------------------
__global__ __launch_bounds__(256) void wconv_kernel(
    const float* __restrict__ w_qkv, const float* __restrict__ w_proj,
    bf16_t* __restrict__ wb)
{
  int idx4 = (blockIdx.x * 256 + threadIdx.x) * 4;
  const float* src = (idx4 < 196608) ? (w_qkv + idx4) : (w_proj + (idx4 - 196608));
  float4 f = *(const float4*)src;
  bf16_t o[4] = {(bf16_t)f.x, (bf16_t)f.y, (bf16_t)f.z, (bf16_t)f.w};
  *(uint2*)(wb + idx4) = *(const uint2*)o;
}

__device__ __forceinline__ void cvt8_store(bf16_t* dst, float4 f0, float4 f1) {
  bf16_t t8[8] = {(bf16_t)f0.x, (bf16_t)f0.y, (bf16_t)f0.z, (bf16_t)f0.w,
                  (bf16_t)f1.x, (bf16_t)f1.y, (bf16_t)f1.z, (bf16_t)f1.w};
  *(uint4*)dst = *(const uint4*)t8;
}

// ---------------------------------------------------------------------------
// Kernel 1: per-token attention, T=4 tiles of 32 tokens per block (grid 784).
// X(t+1) prefetched to regs during tile t; B weight fragments streamed from
// L2 with depth-3 rolling register pipeline (static slot indices via macros);
// softmax/PV use 2-deep e-pipelined LDS bursts. 4 barriers/tile.
// ---------------------------------------------------------------------------
#define T_TILES 4
#define XS_S 272   // row stride (bf16) for Xs: 544B, 16B-aligned
#define QK_S 520   // row stride (bf16) for QK/V: 1040B, 16B-aligned

// GEMM step: 2 M-frags x 4 N-frags, consume Bc, then refill Bc with k+3
#define GSTEP(ACC, Bc, WBASE, kk)                                              \
  { bf16x8 A0_ = *(const bf16x8*)(&Xs[l16][(kk) * 32 + quad * 8]);             \
    bf16x8 A1_ = *(const bf16x8*)(&Xs[16 + l16][(kk) * 32 + quad * 8]);        \
    _Pragma("unroll") for (int j = 0; j < 4; ++j) {                            \
      ACC[0][j] = MFMA16(A0_, Bc[j], ACC[0][j]);                               \
      ACC[1][j] = MFMA16(A1_, Bc[j], ACC[1][j]);                               \
    }                                                                          \
    if ((kk) + 3 < 8) loadB(Bc, WBASE, (kk) + 3); }

#define LOADKV(dst, ee)                                                        \
  { _Pragma("unroll") for (int u = 0; u < 4; ++u)                              \
      dst[u] = *(const bf16x8*)(&QK[t_][256 + (ee) * 32 + u * 8]); }
#define SCORE(kv, ee)                                                          \
  { float a_ = 0.f;                                                            \
    _Pragma("unroll") for (int u = 0; u < 4; ++u)                              \
      _Pragma("unroll") for (int d = 0; d < 8; ++d)                            \
        a_ += qf[u * 8 + d] * (float)kv[u][d];                                 \
    sc[ee] = a_; }

#define LOADVV(dst, ee)                                                        \
  { _Pragma("unroll") for (int u = 0; u < 4; ++u)                              \
      dst[u] = *(const bf16x8*)(&QK[t_][(ee) * 32 + u * 8]); }
#define PVACC(vv, ee)                                                          \
  { float pe_ = p_[ee];                                                        \
    _Pragma("unroll") for (int u = 0; u < 4; ++u)                              \
      _Pragma("unroll") for (int d = 0; d < 8; ++d)                            \
        pre[u * 8 + d] += pe_ * (float)vv[u][d]; }

__global__ __launch_bounds__(512, 4) void attn_kernel(
    const float* __restrict__ x,
    const bf16_t* __restrict__ wb,
    float* __restrict__ outf,
    bf16_t* __restrict__ preb)          // non-null: write pre as bf16 here
{
  __shared__ __align__(16) bf16_t Xs[32][XS_S];   // 17.0 KB  X tile
  __shared__ __align__(16) bf16_t QK[32][QK_S];   // 32.5 KB  Q|K, V in 0..255

  const int tid = threadIdx.x;
  const int wave = tid >> 6, lane = tid & 63, quad = lane >> 4, l16 = lane & 15;
  const float scale = 0.17677669529663687f;       // 32^-0.5

  const int xs0 = tid >> 5;             // rows xs0 and xs0+16
  const int xg0 = (tid & 31) * 8;

  auto loadB = [&](bf16x8 (&dst)[4], const bf16_t* wbase, int k) {
#pragma unroll
    for (int j = 0; j < 4; ++j)
      dst[j] = *(const bf16x8*)(wbase + (j * 16 + l16) * 256 + k * 32 + quad * 8);
  };

  // X prefetch regs (tile t+1)
  float4 xf00, xf01, xf10, xf11;
  auto pfIssue = [&](int tt) {
    const float* xb = x + ((long)(blockIdx.x * T_TILES + tt)) * 32 * 256;
    const float* q0 = xb + xs0 * 256 + xg0;
    xf00 = ((const float4*)q0)[0]; xf01 = ((const float4*)q0)[1];
    const float* q1 = q0 + 16 * 256;
    xf10 = ((const float4*)q1)[0]; xf11 = ((const float4*)q1)[1];
  };

  // ---- prologue: tile 0 -> LDS, issue tile 1 prefetch ----
  pfIssue(0);
  cvt8_store(&Xs[xs0][xg0], xf00, xf01);
  cvt8_store(&Xs[xs0 + 16][xg0], xf10, xf11);
  pfIssue(1);
  __syncthreads();

  for (int t = 0; t < T_TILES; ++t) {
    const long tokbase = ((long)blockIdx.x * T_TILES + t) * 32;

    // ---- P1: QK gemm [32x512] = X @ Wqk^T; B depth-3 pipeline ----
    {
      const bf16_t* wq = wb + (long)(wave * 64) * 256;
      floatx4 acc[2][4] = {};
      bf16x8 Bf0[4], Bf1[4], Bf2[4];
      loadB(Bf0, wq, 0); loadB(Bf1, wq, 1); loadB(Bf2, wq, 2);
      GSTEP(acc, Bf0, wq, 0) GSTEP(acc, Bf1, wq, 1) GSTEP(acc, Bf2, wq, 2)
      GSTEP(acc, Bf0, wq, 3) GSTEP(acc, Bf1, wq, 4) GSTEP(acc, Bf2, wq, 5)
      GSTEP(acc, Bf0, wq, 6) GSTEP(acc, Bf1, wq, 7)
#pragma unroll
      for (int i = 0; i < 2; ++i)
#pragma unroll
        for (int j = 0; j < 4; ++j)
#pragma unroll
          for (int r = 0; r < 4; ++r)
            QK[i * 16 + quad * 4 + r][wave * 64 + j * 16 + l16] = (bf16_t)acc[i][j][r];
    }
    __syncthreads();   // (1) QK ready

    // ---- P2: waves 0-3 softmax | waves 4-7 V gemm ----
    float p_[8];
    floatx4 vacc[2][4];
    if (wave < 4) {
      const int t_ = tid >> 3;                 // token 0..31
      const int h = tid & 7;
      bf16x8 qv[4];
#pragma unroll
      for (int u = 0; u < 4; ++u) qv[u] = *(const bf16x8*)(&QK[t_][h * 32 + u * 8]);
      float qf[32];
#pragma unroll
      for (int u = 0; u < 4; ++u)
#pragma unroll
        for (int d = 0; d < 8; ++d) qf[u * 8 + d] = (float)qv[u][d];
      float sc[8];
      bf16x8 kva[4], kvb[4];
      LOADKV(kva, 0)
      LOADKV(kvb, 1) SCORE(kva, 0)
      LOADKV(kva, 2) SCORE(kvb, 1)
      LOADKV(kvb, 3) SCORE(kva, 2)
      LOADKV(kva, 4) SCORE(kvb, 3)
      LOADKV(kvb, 5) SCORE(kva, 4)
      LOADKV(kva, 6) SCORE(kvb, 5)
      LOADKV(kvb, 7) SCORE(kva, 6)
      SCORE(kvb, 7)
      float mx = -INFINITY;
#pragma unroll
      for (int e = 0; e < 8; ++e) { sc[e] *= scale; mx = fmaxf(mx, sc[e]); }
      float sum = 0.f;
#pragma unroll
      for (int e = 0; e < 8; ++e) { p_[e] = __expf(sc[e] - mx); sum += p_[e]; }
      float rs = 1.0f / sum;
#pragma unroll
      for (int e = 0; e < 8; ++e) p_[e] *= rs;
    } else {
      const bf16_t* wv = wb + (long)(512 + (wave - 4) * 64) * 256;
#pragma unroll
      for (int i = 0; i < 2; ++i)
#pragma unroll
        for (int j = 0; j < 4; ++j) vacc[i][j] = (floatx4){0.f, 0.f, 0.f, 0.f};
      bf16x8 Bf0[4], Bf1[4], Bf2[4];
      loadB(Bf0, wv, 0); loadB(Bf1, wv, 1); loadB(Bf2, wv, 2);
      GSTEP(vacc, Bf0, wv, 0) GSTEP(vacc, Bf1, wv, 1) GSTEP(vacc, Bf2, wv, 2)
      GSTEP(vacc, Bf0, wv, 3) GSTEP(vacc, Bf1, wv, 4) GSTEP(vacc, Bf2, wv, 5)
      GSTEP(vacc, Bf0, wv, 6) GSTEP(vacc, Bf1, wv, 7)
    }
    __syncthreads();   // (2) QK reads (softmax) + Xs reads (V gemm) done

    // ---- W: V -> QK[0..255]; X(t+1) -> Xs; issue X(t+2) ----
    if (wave >= 4) {
      const int u = wave - 4;
#pragma unroll
      for (int i = 0; i < 2; ++i)
#pragma unroll
        for (int j = 0; j < 4; ++j)
#pragma unroll
          for (int r = 0; r < 4; ++r)
            QK[i * 16 + quad * 4 + r][u * 64 + j * 16 + l16] = (bf16_t)vacc[i][j][r];
    }
    if (t < T_TILES - 1) {
      cvt8_store(&Xs[xs0][xg0], xf00, xf01);
      cvt8_store(&Xs[xs0 + 16][xg0], xf10, xf11);
      if (t < T_TILES - 2) pfIssue(t + 2);
    }
    __syncthreads();   // (3) V ready, Xs(t+1) ready

    // ---- P3: PV (waves 0-3) + pre store ----
    if (wave < 4) {
      const int t_ = tid >> 3, h = tid & 7;
      float pre[32];
#pragma unroll
      for (int i = 0; i < 32; ++i) pre[i] = 0.f;
      bf16x8 kva[4], kvb[4];
      LOADVV(kva, 0)
      LOADVV(kvb, 1) PVACC(kva, 0)
      LOADVV(kva, 2) PVACC(kvb, 1)
      LOADVV(kvb, 3) PVACC(kva, 2)
      LOADVV(kva, 4) PVACC(kvb, 3)
      LOADVV(kvb, 5) PVACC(kva, 4)
      LOADVV(kva, 6) PVACC(kvb, 5)
      LOADVV(kvb, 7) PVACC(kva, 6)
      PVACC(kvb, 7)
      if (preb) {
        bf16_t* op = preb + (tokbase + t_) * 256 + h * 32;
#pragma unroll
        for (int u = 0; u < 4; ++u) {
          bf16_t t8[8];
#pragma unroll
          for (int d = 0; d < 8; ++d) t8[d] = (bf16_t)pre[u * 8 + d];
          *(uint4*)(op + u * 8) = *(const uint4*)t8;
        }
      } else {
        float* op = outf + (tokbase + t_) * 256 + h * 32;
#pragma unroll
        for (int u = 0; u < 8; ++u) {
          float4 f = {pre[u * 4], pre[u * 4 + 1], pre[u * 4 + 2], pre[u * 4 + 3]};
          ((float4*)op)[u] = f;
        }
      }
    }
    if (t < T_TILES - 1) __syncthreads();  // (4) PV reads done before next P1 writes
  }
}

// ---------------------------------------------------------------------------
// Kernel 2: stripe projection. Block = (b, wh, half): 4 windows of one
// 7-row image stripe (grid 512). Gather for window w+1 issued during GEMM of
// window w; B streamed depth-3 from L2. Scramble: flat = h*1568+s*32+d ->
// Sc[flat>>8][flat&255] (offsets precomputed, constant across windows).
// ---------------------------------------------------------------------------
#define SC_S 264   // row stride (bf16): 528B, 16B-aligned
#define NW 4

#define PSTEP(Bc, kk)                                                          \
  { bf16x8 A_[4];                                                              \
    _Pragma("unroll") for (int i2 = 0; i2 < 4; ++i2) {                         \
      int mr_ = i2 * 16 + l16; if (mr_ > 48) mr_ = 48;                         \
      A_[i2] = *(const bf16x8*)(&Sc[mr_][(kk) * 32 + quad * 8]); }             \
    _Pragma("unroll") for (int i2 = 0; i2 < 4; ++i2) {                         \
      acc[i2][0] = MFMA16(A_[i2], Bc[0], acc[i2][0]);                          \
      acc[i2][1] = MFMA16(A_[i2], Bc[1], acc[i2][1]); }                        \
    if ((kk) + 3 < 8) loadBp(Bc, (kk) + 3); }

__global__ __launch_bounds__(512, 4) void proj_stripe_kernel(
    const bf16_t* __restrict__ wb,
    const float* __restrict__ b_proj,
    float* __restrict__ out,
    const bf16_t* __restrict__ preb)
{
  __shared__ __align__(16) bf16_t Sc[49][SC_S];   // 25.9 KB scrambled pre
  __shared__ int trow0[49];

  const int blk = blockIdx.x;            // 0..511
  const int b = blk >> 4, wh = (blk >> 1) & 7, half = blk & 1;
  const int rowbase = b * 3136 + wh * 7 * 56;
  const int tid = threadIdx.x;
  const int wave = tid >> 6, lane = tid & 63, quad = lane >> 4, l16 = lane & 15;
  const int ww0 = half * 4;

  if (tid < 49) trow0[tid] = rowbase + (tid / 7) * 56 + (tid % 7);

  // gather geometry (constant across windows): chunk c reads row s_c = xs+16c,
  // 8 bf16 at col g8*8; writes Sc at flat = (g8>>2)*1568 + s_c*32 + (g8&3)*8.
  const int g8 = tid & 31, xs = tid >> 5;
  const int s0 = xs, s1 = xs + 16, s2 = xs + 32;           // s3 = 48 (tid<32)
  const int srow0 = (s0 / 7) * 56 + (s0 % 7);
  const int srow1 = (s1 / 7) * 56 + (s1 % 7);
  const int srow2 = (s2 / 7) * 56 + (s2 % 7);
  const int srow3 = 342;                                    // 48 -> 6*56+6
  const int fl0 = (g8 >> 2) * 1568 + s0 * 32 + (g8 & 3) * 8;
  const int fl1 = (g8 >> 2) * 1568 + s1 * 32 + (g8 & 3) * 8;
  const int fl2 = (g8 >> 2) * 1568 + s2 * 32 + (g8 & 3) * 8;
  const int fl3 = (g8 >> 2) * 1568 + 48 * 32 + (g8 & 3) * 8;
  bf16_t* dp0 = &Sc[fl0 >> 8][fl0 & 255];
  bf16_t* dp1 = &Sc[fl1 >> 8][fl1 & 255];
  bf16_t* dp2 = &Sc[fl2 >> 8][fl2 & 255];
  bf16_t* dp3 = &Sc[fl3 >> 8][fl3 & 255];

  bf16x8 g0, g1, g2, g3;
  auto gLoad = [&](int ww) {
    const bf16_t* pb = preb + (long)(rowbase + ww * 7) * 256 + g8 * 8;
    g0 = *(const bf16x8*)(pb + (long)srow0 * 256);
    g1 = *(const bf16x8*)(pb + (long)srow1 * 256);
    g2 = *(const bf16x8*)(pb + (long)srow2 * 256);
    if (tid < 32) g3 = *(const bf16x8*)(pb + (long)srow3 * 256);
  };
  auto gStore = [&]() {
    *(bf16x8*)dp0 = g0; *(bf16x8*)dp1 = g1; *(bf16x8*)dp2 = g2;
    if (tid < 32) *(bf16x8*)dp3 = g3;
  };

  const bf16_t* wp = wb + 196608 + (long)(wave * 32) * 256;
  auto loadBp = [&](bf16x8 (&dst)[2], int k) {
#pragma unroll
    for (int j = 0; j < 2; ++j)
      dst[j] = *(const bf16x8*)(wp + (j * 16 + l16) * 256 + k * 32 + quad * 8);
  };
  const float bv0 = b_proj[wave * 32 + l16];
  const float bv1 = b_proj[wave * 32 + 16 + l16];

  // ---- prologue: window ww0 -> Sc, issue ww0+1 ----
  gLoad(ww0);
  gStore();
  gLoad(ww0 + 1);
  __syncthreads();   // Sc ready, trow0 ready

  for (int w = 0; w < NW; ++w) {
    const int ww = ww0 + w;
    // ---- GEMM: out(49x256) = Sc @ Wp^T + bias ----
    floatx4 acc[4][2] = {};
    {
      bf16x8 Bf0[2], Bf1[2], Bf2[2];
      loadBp(Bf0, 0); loadBp(Bf1, 1); loadBp(Bf2, 2);
      PSTEP(Bf0, 0) PSTEP(Bf1, 1) PSTEP(Bf2, 2) PSTEP(Bf0, 3)
      PSTEP(Bf1, 4) PSTEP(Bf2, 5) PSTEP(Bf0, 6) PSTEP(Bf1, 7)
    }
#pragma unroll
    for (int i2 = 0; i2 < 4; ++i2)
#pragma unroll
      for (int r = 0; r < 4; ++r) {
        int m = i2 * 16 + quad * 4 + r;
        if (m < 49) {
          float* orow = out + (long)(trow0[m] + ww * 7) * 256 + wave * 32 + l16;
          orow[0]  = acc[i2][0][r] + bv0;
          orow[16] = acc[i2][1][r] + bv1;
        }
      }
    if (w + 1 < NW) {
      __syncthreads();           // all Sc reads done
      gStore();                  // Sc <- window ww+1
      if (w + 2 < NW) gLoad(ww0 + w + 2);
      __syncthreads();           // Sc ready
    }
  }
}

// ---------------------------------------------------------------------------
// Fallback proj (fp32 in-place on out), used only when workspace too small.
// ---------------------------------------------------------------------------
__global__ __launch_bounds__(512, 4) void proj_kernel_f32(
    const bf16_t* __restrict__ wb,
    const float* __restrict__ b_proj,
    float* out)
{
  __shared__ __align__(16) bf16_t Sc[49][SC_S];
  __shared__ int trow[49];
  const int n = blockIdx.x;
  const int b = n >> 6, wh = (n >> 3) & 7, ww = n & 7;
  const int tid = threadIdx.x;
  const int wave = tid >> 6, lane = tid & 63, quad = lane >> 4, l16 = lane & 15;

  const bf16_t* wp = wb + 196608 + (long)(wave * 32) * 256;
  auto loadBp = [&](bf16x8 (&dst)[2], int k) {
#pragma unroll
    for (int j = 0; j < 2; ++j)
      dst[j] = *(const bf16x8*)(wp + (j * 16 + l16) * 256 + k * 32 + quad * 8);
  };
  const float bv0 = b_proj[wave * 32 + l16];
  const float bv1 = b_proj[wave * 32 + 16 + l16];

  if (tid < 49) {
    int i = tid / 7, j = tid % 7;
    trow[tid] = b * 3136 + (wh * 7 + i) * 56 + ww * 7 + j;
  }
  __syncthreads();
  for (int idx = tid; idx < 49 * 32; idx += 512) {
    int s = idx >> 5, c8 = idx & 31;
    const float* p = out + (long)trow[s] * 256 + c8 * 8;
    float4 f0 = ((const float4*)p)[0];
    float4 f1 = ((const float4*)p)[1];
    int flat = (c8 >> 2) * 1568 + s * 32 + (c8 & 3) * 8;
    cvt8_store(&Sc[flat >> 8][flat & 255], f0, f1);
  }
  __syncthreads();
  floatx4 acc[4][2] = {};
  {
    bf16x8 Bf0[2], Bf1[2], Bf2[2];
    loadBp(Bf0, 0); loadBp(Bf1, 1); loadBp(Bf2, 2);
    PSTEP(Bf0, 0) PSTEP(Bf1, 1) PSTEP(Bf2, 2) PSTEP(Bf0, 3)
    PSTEP(Bf1, 4) PSTEP(Bf2, 5) PSTEP(Bf0, 6) PSTEP(Bf1, 7)
  }
#pragma unroll
  for (int i2 = 0; i2 < 4; ++i2)
#pragma unroll
    for (int r = 0; r < 4; ++r) {
      int m = i2 * 16 + quad * 4 + r;
      if (m < 49) {
        float* orow = out + (long)trow[m] * 256 + wave * 32 + l16;
        orow[0]  = acc[i2][0][r] + bv0;
        orow[16] = acc[i2][1][r] + bv1;
      }
    }
}

// ---------------------------------------------------------------------------
extern "C" void kernel_launch(void* const* d_in, const int* in_sizes, int n_in,
                              void* d_out, int out_size, void* d_ws, size_t ws_size,
                              hipStream_t stream) {
  (void)in_sizes; (void)n_in; (void)out_size;
  const float* x      = (const float*)d_in[0];
  const float* w_qkv  = (const float*)d_in[1];
  const float* w_proj = (const float*)d_in[2];
  const float* b_proj = (const float*)d_in[3];
  float* out = (float*)d_out;
  bf16_t* wb = (bf16_t*)d_ws;   // 262144 bf16 = 512 KB

  // bf16 pre buffer (100352*256*2 = 51.4 MB) if workspace allows
  bf16_t* preb = nullptr;
  if (ws_size >= (size_t)524288 + 51380224) preb = wb + 262144;

  wconv_kernel<<<dim3(256), 256, 0, stream>>>(w_qkv, w_proj, wb);
  attn_kernel<<<dim3(784), 512, 0, stream>>>(x, wb, out, preb);
  if (preb)
    proj_stripe_kernel<<<dim3(512), 512, 0, stream>>>(wb, b_proj, out, preb);
  else
    proj_kernel_f32<<<dim3(2048), 512, 0, stream>>>(wb, b_proj, out);
}

// Round 6
// 279.948 us; speedup vs baseline: 2.1211x; 2.1211x over previous
//
#include <hip/hip_runtime.h>
#include <hip/hip_bf16.h>

typedef __bf16 bf16_t;
typedef bf16_t bf16x8 __attribute__((ext_vector_type(8)));
typedef float floatx4 __attribute__((ext_vector_type(4)));

#define MFMA16(a, b, c) __builtin_amdgcn_mfma_f32_16x16x32_bf16((a), (b), (c), 0, 0, 0)

// ---------------------------------------------------------------------------
// One-time weight convert fp32 -> bf16, PRE-SWIZZLED into MFMA fragment order
// so kernel-side B loads are contiguous 1KB wave-reads.
//
// QKV region (wb[0 .. 196607]): 12 panels of 64 cols. chunk = p*32 + k*4 + j
// (p in [0,12), k in [0,8), j in [0,4)), 512 bf16 per chunk. Element (lane,d)
// of a chunk = w_qkv[(p*64 + j*16 + (lane&15))*256 + k*32 + (lane>>4)*8 + d].
//
// PROJ region (wb[196608 .. 262143]): 8 panels of 32 cols. chunk = p*16+k*2+j
// (j in [0,2)). Element (lane,d) =
//   w_proj[(p*32 + j*16 + (lane&15))*256 + k*32 + (lane>>4)*8 + d].
// ---------------------------------------------------------------------------
__global__ __launch_bounds__(256) void wconv_kernel(
    const float* __restrict__ w_qkv, const float* __restrict__ w_proj,
    bf16_t* __restrict__ wb)
{
  int i = blockIdx.x * 256 + threadIdx.x;      // 0 .. 32767, one 16B chunk each
  const float* src;
  bf16_t* dst;
  if (i < 24576) {                             // qkv: 384 chunks x 64 lanes
    int chunk = i >> 6, l = i & 63;
    int p = chunk >> 5, rem = chunk & 31, k = rem >> 2, j = rem & 3;
    int col = p * 64 + j * 16 + (l & 15);
    int kk = k * 32 + (l >> 4) * 8;
    src = w_qkv + col * 256 + kk;
    dst = wb + (i << 3);
  } else {                                     // proj: 128 chunks x 64 lanes
    int ip = i - 24576;
    int chunk = ip >> 6, l = ip & 63;
    int p = chunk >> 4, rem = chunk & 15, k = rem >> 1, j = rem & 1;
    int col = p * 32 + j * 16 + (l & 15);
    int kk = k * 32 + (l >> 4) * 8;
    src = w_proj + col * 256 + kk;
    dst = wb + 196608 + (ip << 3);
  }
  float4 f0 = ((const float4*)src)[0];
  float4 f1 = ((const float4*)src)[1];
  bf16_t t8[8] = {(bf16_t)f0.x, (bf16_t)f0.y, (bf16_t)f0.z, (bf16_t)f0.w,
                  (bf16_t)f1.x, (bf16_t)f1.y, (bf16_t)f1.z, (bf16_t)f1.w};
  *(uint4*)dst = *(const uint4*)t8;
}

__device__ __forceinline__ void cvt8_store(bf16_t* dst, float4 f0, float4 f1) {
  bf16_t t8[8] = {(bf16_t)f0.x, (bf16_t)f0.y, (bf16_t)f0.z, (bf16_t)f0.w,
                  (bf16_t)f1.x, (bf16_t)f1.y, (bf16_t)f1.z, (bf16_t)f1.w};
  *(uint4*)dst = *(const uint4*)t8;
}

// ---------------------------------------------------------------------------
// Kernel 1: per-token attention on contiguous 32-token tiles (grid 3136).
// Round-4 structure; B-fragment loads are now contiguous 1KB wave-reads from
// the swizzled weight regions. B double-buffered one k-step ahead.
// ---------------------------------------------------------------------------
#define XS_S 272   // row stride (bf16) for Xs: 544B, 16B-aligned
#define QK_S 520   // row stride (bf16) for QK/V: 1040B, 16B-aligned

__global__ __launch_bounds__(512, 4) void attn_kernel(
    const float* __restrict__ x,
    const bf16_t* __restrict__ wb,
    float* __restrict__ outf,
    bf16_t* __restrict__ preb)          // non-null: write pre as bf16 here
{
  __shared__ __align__(16) bf16_t Xs[32][XS_S];   // 17.0 KB  X tile
  __shared__ __align__(16) bf16_t QK[32][QK_S];   // 32.5 KB  Q|K, later V in 0..255

  const int tid = threadIdx.x;
  const int wave = tid >> 6, lane = tid & 63, quad = lane >> 4, l16 = lane & 15;
  const long base = (long)blockIdx.x * 32;
  const float scale = 0.17677669529663687f;       // 32^-0.5

  // swizzled fragment load: panel pan, k-step k -> 4 N-frags, each 1KB wave-read
  auto loadB = [&](bf16x8* dst, int pan, int k) {
    const bf16_t* c = wb + ((long)(pan * 32 + k * 4) << 9) + lane * 8;
#pragma unroll
    for (int j = 0; j < 4; ++j) dst[j] = *(const bf16x8*)(c + (j << 9));
  };

  // ---- P0: stage X: 32x256 fp32 -> bf16 LDS, fully coalesced ----
  const float* xb = x + base * 256;
#pragma unroll
  for (int it = 0; it < 2; ++it) {
    int idx = tid + it * 512;                 // 0..1023 groups of 8 floats
    int s = idx >> 5, g = (idx & 31) * 8;
    const float* p = xb + s * 256 + g;
    float4 f0 = ((const float4*)p)[0];
    float4 f1 = ((const float4*)p)[1];
    cvt8_store(&Xs[s][g], f0, f1);
  }
  __syncthreads();

  // ---- P1: QK gemm [32x512] = X @ Wqk^T, k-pipelined B loads ----
  {
    floatx4 acc[2][4] = {};
    bf16x8 Ba[4], Bb[4];
    loadB(Ba, wave, 0);
#pragma unroll
    for (int k = 0; k < 8; ++k) {
      const bf16x8* cur = (k & 1) ? Bb : Ba;
      if (k < 7) loadB((k & 1) ? Ba : Bb, wave, k + 1);
      bf16x8 A0 = *(const bf16x8*)(&Xs[l16][k * 32 + quad * 8]);
      bf16x8 A1 = *(const bf16x8*)(&Xs[16 + l16][k * 32 + quad * 8]);
#pragma unroll
      for (int j = 0; j < 4; ++j) {
        acc[0][j] = MFMA16(A0, cur[j], acc[0][j]);
        acc[1][j] = MFMA16(A1, cur[j], acc[1][j]);
      }
    }
#pragma unroll
    for (int i = 0; i < 2; ++i)
#pragma unroll
      for (int j = 0; j < 4; ++j)
#pragma unroll
        for (int r = 0; r < 4; ++r)
          QK[i * 16 + quad * 4 + r][wave * 64 + j * 16 + l16] = (bf16_t)acc[i][j][r];
  }
  __syncthreads();

  // ---- P2: waves 0-3: per-token 8x8 head-mix softmax (e-half bursts)
  //          waves 4-7: V gemm [32x256] = X @ Wv^T (k-pipelined) ----
  float p_[8];          // probs (waves 0-3)
  floatx4 vacc[2][4];   // V acc (waves 4-7)
  if (wave < 4) {
    const int t = tid >> 3, h = tid & 7;     // 256 tasks = 32 tok x 8 heads
    bf16x8 qv[4];
#pragma unroll
    for (int u = 0; u < 4; ++u) qv[u] = *(const bf16x8*)(&QK[t][h * 32 + u * 8]);
    float qf[32];
#pragma unroll
    for (int u = 0; u < 4; ++u)
#pragma unroll
      for (int d = 0; d < 8; ++d) qf[u * 8 + d] = (float)qv[u][d];
    float sc[8];
#pragma unroll
    for (int eh = 0; eh < 2; ++eh) {
      bf16x8 kv[4][4];
#pragma unroll
      for (int e2 = 0; e2 < 4; ++e2)
#pragma unroll
        for (int u = 0; u < 4; ++u)
          kv[e2][u] = *(const bf16x8*)(&QK[t][256 + (eh * 4 + e2) * 32 + u * 8]);
#pragma unroll
      for (int e2 = 0; e2 < 4; ++e2) {
        float a = 0.f;
#pragma unroll
        for (int u = 0; u < 4; ++u)
#pragma unroll
          for (int d = 0; d < 8; ++d) a += qf[u * 8 + d] * (float)kv[e2][u][d];
        sc[eh * 4 + e2] = a;
      }
    }
    float mx = -INFINITY;
#pragma unroll
    for (int e = 0; e < 8; ++e) { sc[e] *= scale; mx = fmaxf(mx, sc[e]); }
    float sum = 0.f;
#pragma unroll
    for (int e = 0; e < 8; ++e) { p_[e] = __expf(sc[e] - mx); sum += p_[e]; }
    float rs = 1.0f / sum;
#pragma unroll
    for (int e = 0; e < 8; ++e) p_[e] *= rs;
  } else {
    const int pan = 8 + (wave - 4);          // V panels 8..11
#pragma unroll
    for (int i = 0; i < 2; ++i)
#pragma unroll
      for (int j = 0; j < 4; ++j) vacc[i][j] = (floatx4){0.f, 0.f, 0.f, 0.f};
    bf16x8 Ba[4], Bb[4];
    loadB(Ba, pan, 0);
#pragma unroll
    for (int k = 0; k < 8; ++k) {
      const bf16x8* cur = (k & 1) ? Bb : Ba;
      if (k < 7) loadB((k & 1) ? Ba : Bb, pan, k + 1);
      bf16x8 A0 = *(const bf16x8*)(&Xs[l16][k * 32 + quad * 8]);
      bf16x8 A1 = *(const bf16x8*)(&Xs[16 + l16][k * 32 + quad * 8]);
#pragma unroll
      for (int j = 0; j < 4; ++j) {
        vacc[0][j] = MFMA16(A0, cur[j], vacc[0][j]);
        vacc[1][j] = MFMA16(A1, cur[j], vacc[1][j]);
      }
    }
  }
  __syncthreads();   // q,k LDS reads done; V acc ready

  if (wave >= 4) {   // V overwrites cols 0..255 of QK
    const int u = wave - 4;
#pragma unroll
    for (int i = 0; i < 2; ++i)
#pragma unroll
      for (int j = 0; j < 4; ++j)
#pragma unroll
        for (int r = 0; r < 4; ++r)
          QK[i * 16 + quad * 4 + r][u * 64 + j * 16 + l16] = (bf16_t)vacc[i][j][r];
  }
  __syncthreads();   // V ready

  // ---- P3: PV (waves 0-3), e-half bursts; store pre ----
  if (wave < 4) {
    const int t = tid >> 3, h = tid & 7;
    float pre[32];
#pragma unroll
    for (int i = 0; i < 32; ++i) pre[i] = 0.f;
#pragma unroll
    for (int eh = 0; eh < 2; ++eh) {
      bf16x8 vv[4][4];
#pragma unroll
      for (int e2 = 0; e2 < 4; ++e2)
#pragma unroll
        for (int u = 0; u < 4; ++u)
          vv[e2][u] = *(const bf16x8*)(&QK[t][(eh * 4 + e2) * 32 + u * 8]);
#pragma unroll
      for (int e2 = 0; e2 < 4; ++e2) {
        float pe = p_[eh * 4 + e2];
#pragma unroll
        for (int u = 0; u < 4; ++u)
#pragma unroll
          for (int d = 0; d < 8; ++d) pre[u * 8 + d] += pe * (float)vv[e2][u][d];
      }
    }
    if (preb) {
      bf16_t* op = preb + (base + t) * 256 + h * 32;
#pragma unroll
      for (int u = 0; u < 4; ++u) {
        bf16_t t8[8];
#pragma unroll
        for (int d = 0; d < 8; ++d) t8[d] = (bf16_t)pre[u * 8 + d];
        *(uint4*)(op + u * 8) = *(const uint4*)t8;
      }
    } else {
      float* op = outf + (base + t) * 256 + h * 32;
#pragma unroll
      for (int u = 0; u < 8; ++u) {
        float4 f = {pre[u * 4], pre[u * 4 + 1], pre[u * 4 + 2], pre[u * 4 + 3]};
        ((float4*)op)[u] = f;
      }
    }
  }
}

// ---------------------------------------------------------------------------
// Kernel 2: per-window scramble + projection (grid 2048, round-4 structure).
// flat = h*1568 + s*32 + d -> scram row flat>>8, chan flat&255 (within window).
// B preloaded in two k-halves from the SWIZZLED proj region (contiguous 1KB
// wave-reads); half 0 issued before the gather. A double-buffered per k-step.
// ---------------------------------------------------------------------------
#define SC_S 264   // row stride (bf16): 528B, 16B-aligned

__global__ __launch_bounds__(512, 4) void proj_kernel(
    const bf16_t* __restrict__ wb,
    const float* __restrict__ b_proj,
    float* out,
    const bf16_t* __restrict__ preb)
{
  __shared__ __align__(16) bf16_t Sc[49][SC_S];   // 25.9 KB scrambled pre
  __shared__ int trow[49];

  const int n = blockIdx.x;              // window id 0..2047
  const int b = n >> 6, wh = (n >> 3) & 7, ww = n & 7;
  const int tid = threadIdx.x;
  const int wave = tid >> 6, lane = tid & 63, quad = lane >> 4, l16 = lane & 15;

  // swizzled proj fragment load: chunk = wave*16 + k*2 + j, 512B wave-chunks
  auto loadB2 = [&](bf16x8 (*dst)[2], int k0) {
#pragma unroll
    for (int kk = 0; kk < 4; ++kk)
#pragma unroll
      for (int j = 0; j < 2; ++j)
        dst[kk][j] = *(const bf16x8*)(wb + 196608 +
            ((long)(wave * 16 + (k0 + kk) * 2 + j) << 9) + lane * 8);
  };
  // ---- B half 0 preload: issued before the gather, hides under staging ----
  bf16x8 Bh0[4][2];
  loadB2(Bh0, 0);
  float bv[2];
#pragma unroll
  for (int j = 0; j < 2; ++j) bv[j] = b_proj[wave * 32 + j * 16 + l16];

  if (tid < 49) {
    int i = tid / 7, j = tid % 7;
    trow[tid] = b * 3136 + (wh * 7 + i) * 56 + ww * 7 + j;
  }
  __syncthreads();

  // ---- stage + scramble: 49 rows x 32 chunks of 8 values ----
  if (preb) {
    for (int idx = tid; idx < 49 * 32; idx += 512) {
      int s = idx >> 5, g8 = idx & 31;
      bf16x8 v = *(const bf16x8*)(preb + (long)trow[s] * 256 + g8 * 8);
      int flat = (g8 >> 2) * 1568 + s * 32 + (g8 & 3) * 8;   // h*1568 + s*32 + d
      *(bf16x8*)(&Sc[flat >> 8][flat & 255]) = v;
    }
  } else {
    for (int idx = tid; idx < 49 * 32; idx += 512) {
      int s = idx >> 5, g8 = idx & 31;
      const float* p = out + (long)trow[s] * 256 + g8 * 8;
      float4 f0 = ((const float4*)p)[0];
      float4 f1 = ((const float4*)p)[1];
      int flat = (g8 >> 2) * 1568 + s * 32 + (g8 & 3) * 8;
      cvt8_store(&Sc[flat >> 8][flat & 255], f0, f1);
    }
  }
  // ---- B half 1: issue before the barrier ----
  bf16x8 Bh1[4][2];
  loadB2(Bh1, 4);
  __syncthreads();

  // ---- proj gemm: out(49x256) = Sc @ Wp^T + bias; A double-buffered ----
  {
    floatx4 acc[4][2] = {};
    bf16x8 Aa[4], Ab[4];
    auto loadA = [&](bf16x8* dst, int k) {
#pragma unroll
      for (int i = 0; i < 4; ++i) {
        int mr = i * 16 + l16; if (mr > 48) mr = 48;
        dst[i] = *(const bf16x8*)(&Sc[mr][k * 32 + quad * 8]);
      }
    };
    loadA(Aa, 0);
#pragma unroll
    for (int k = 0; k < 8; ++k) {
      const bf16x8* curA = (k & 1) ? Ab : Aa;
      if (k < 7) loadA((k & 1) ? Aa : Ab, k + 1);
#pragma unroll
      for (int i = 0; i < 4; ++i)
#pragma unroll
        for (int j = 0; j < 2; ++j)
          acc[i][j] = MFMA16(curA[i], (k < 4) ? Bh0[k][j] : Bh1[k - 4][j], acc[i][j]);
    }
#pragma unroll
    for (int j = 0; j < 2; ++j) {
      int col = wave * 32 + j * 16 + l16;
#pragma unroll
      for (int i = 0; i < 4; ++i)
#pragma unroll
        for (int r = 0; r < 4; ++r) {
          int m = i * 16 + quad * 4 + r;
          if (m < 49) out[(long)trow[m] * 256 + col] = acc[i][j][r] + bv[j];
        }
    }
  }
}

// ---------------------------------------------------------------------------
extern "C" void kernel_launch(void* const* d_in, const int* in_sizes, int n_in,
                              void* d_out, int out_size, void* d_ws, size_t ws_size,
                              hipStream_t stream) {
  (void)in_sizes; (void)n_in; (void)out_size;
  const float* x      = (const float*)d_in[0];
  const float* w_qkv  = (const float*)d_in[1];
  const float* w_proj = (const float*)d_in[2];
  const float* b_proj = (const float*)d_in[3];
  float* out = (float*)d_out;
  bf16_t* wb = (bf16_t*)d_ws;   // 262144 bf16 = 512 KB

  // bf16 pre buffer (100352*256*2 = 51.4 MB) if workspace allows
  bf16_t* preb = nullptr;
  if (ws_size >= (size_t)524288 + 51380224) preb = wb + 262144;

  wconv_kernel<<<dim3(128), 256, 0, stream>>>(w_qkv, w_proj, wb);
  attn_kernel<<<dim3(3136), 512, 0, stream>>>(x, wb, out, preb);
  proj_kernel<<<dim3(2048), 512, 0, stream>>>(wb, b_proj, out, preb);
}